// Round 6
// baseline (552.462 us; speedup 1.0000x reference)
//
#include <hip/hip_runtime.h>
#include <math.h>

// Problem constants (B,H,T,S,D,V) = (4,16,512,512,1024,32000)
constexpr int NB = 4;
constexpr int NH = 16;
constexpr int NT = 512;
constexpr int NS = 512;
constexpr int ND = 1024;
constexpr int NV = 32000;
constexpr int NV4 = NV / 4;          // 8000 float4 per row
constexpr float EPS = 1e-12f;

constexpr int HSIZE = 2048;  // >= 4x max distinct ids per row (512)
constexpr int BLK = 512;

// ---------------------------------------------------------------------------
// K2: e_proj[b,s] = dot(encoder_last_hidden_state[b,s,:], w_enc)   (D=1024)
// One wave (64 lanes) per (b,s).  ~8 MB read; tiny.
// ---------------------------------------------------------------------------
__global__ void eproj_kernel(const float* __restrict__ E, const float* __restrict__ w_enc,
                             float* __restrict__ e_proj) {
    int gid = blockIdx.x * blockDim.x + threadIdx.x;
    int w = gid >> 6;
    int lane = gid & 63;
    if (w >= NB * NS) return;
    const float4* e4 = (const float4*)(E + (size_t)w * ND);
    const float4* w4 = (const float4*)w_enc;
    float acc = 0.f;
#pragma unroll
    for (int i = lane; i < ND / 4; i += 64) {
        float4 a = e4[i], b = w4[i];
        acc += a.x * b.x + a.y * b.y + a.z * b.z + a.w * b.w;
    }
    for (int off = 32; off > 0; off >>= 1) acc += __shfl_down(acc, off, 64);
    if (lane == 0) e_proj[w] = acc;
}

__device__ __forceinline__ float esum4(float4 v) {
    return __expf(v.x) + __expf(v.y) + __expf(v.z) + __expf(v.w);
}

// ---------------------------------------------------------------------------
// Mega kernel: one 512-thread block per (b,t) row.
// Round-5 post-mortem: compiler rematerializes the pass-B row re-read
// (VGPR=32, re-read is L2/L3-hot and free of HBM traffic), so we keep the
// two-pass structure and instead attack exposed latency:
//  - 512 threads, __launch_bounds__(512,8): 4 blocks/CU resident (32 waves,
//    full occupancy), grid 2048 = 2 rounds.  Round 5 had only 2 blocks/CU:
//    every barrier/reduce window left one peer to feed HBM.  Round 3's
//    256-thr regression was the 1-round lockstep, not block size itself.
//  - 3 barriers (was 4): wave shfl-reduce -> LDS atomicAdd to {sZ,sG} ->
//    one barrier -> every thread duplicates the tiny finalize (sigmoid/log).
//  - block-parity phase swap: even blocks stream the row first, odd blocks
//    do catt/gate/hash first -> co-resident blocks de-correlate in round 1.
// ---------------------------------------------------------------------------
__global__ __launch_bounds__(512, 8) void out_kernel(
    const float* __restrict__ A,        // decoder_attention (B,H,T,S)
    const float* __restrict__ logits,   // (B,T,V)
    const int*   __restrict__ ids,      // (B,S)
    const float* __restrict__ dlhs,     // (B,T,D)
    const float* __restrict__ die,      // (B,T,D)
    const float* __restrict__ e_proj,   // (B,S)
    const float* __restrict__ w_logits, const float* __restrict__ w_embeds,
    const float* __restrict__ b_logits, const float* __restrict__ b_embeds,
    const float* __restrict__ b_enc, const float* __restrict__ bias,
    float* __restrict__ out) {
    __shared__ int   hkey[HSIZE];
    __shared__ float hval[HSIZE];
    __shared__ float sZ, sG;

    const int row = blockIdx.x;       // b*NT + t
    const int tid = threadIdx.x;      // == s index for catt/hash (NS == BLK)
    const int b = row / NT;
    const int t = row % NT;

    // init hash + reduction cells (inserts/atomics happen after B1)
    for (int i = tid; i < HSIZE; i += BLK) {
        hkey[i] = -1;
        hval[i] = 0.f;
    }
    if (tid == 0) { sZ = 0.f; sG = 0.f; }

    // ---- c_att[s=tid]: mean over 16 head-planes (register-resident).
    // Issued before B1 so the 16 loads' latency overlaps the barrier. ----
    const float* Ap = A + ((size_t)b * NH * NT + t) * NS + tid;  // h=0 plane
    float cacc = 0.f;
#pragma unroll
    for (int h = 0; h < NH; ++h) cacc += Ap[(size_t)h * NT * NS];
    const float cmean = cacc * (1.0f / NH);
    __syncthreads();  // B1: hkey/sZ/sG initialized

    float zsum = 0.f, gsum = 0.f;
    const float4* L4 = (const float4*)(logits + (size_t)row * NV);

    // small phase: gate dots + ctx term + hash insert
    auto do_small = [&]() {
        if (tid < ND / 4) {  // 128 threads? no: ND/4 = 256 threads
            const float4* x1 = (const float4*)(dlhs + (size_t)row * ND);
            const float4* w1 = (const float4*)w_logits;
            const float4* x2 = (const float4*)(die + (size_t)row * ND);
            const float4* w2 = (const float4*)w_embeds;
            float4 a0 = x1[tid], b0 = w1[tid];
            gsum += a0.x * b0.x + a0.y * b0.y + a0.z * b0.z + a0.w * b0.w;
            float4 a1 = x2[tid], b1 = w2[tid];
            gsum += a1.x * b1.x + a1.y * b1.y + a1.z * b1.z + a1.w * b1.w;
        }
        // every thread owns one s (BLK == NS)
        gsum += cmean * e_proj[b * NS + tid];
        int id = ids[b * NS + tid];
        unsigned h = ((unsigned)id * 2654435761u) >> 21;  // 11 bits
        for (int probe = 0; probe < HSIZE; ++probe) {     // bounded: <=512 keys
            int prev = atomicCAS(&hkey[h], -1, id);
            if (prev == -1 || prev == id) {
                atomicAdd(&hval[h], cmean);
                break;
            }
            h = (h + 1) & (HSIZE - 1);
        }
    };

    // stream phase: Z partial over the row, 5-deep load batches.
    // NV4 = 8000 = 15*512 + 320: k=0..14 full strides, tail for tid<320.
    auto do_stream = [&]() {
        {
            float4 v0 = L4[tid];
            float4 v1 = L4[tid + 512];
            float4 v2 = L4[tid + 1024];
            float4 v3 = L4[tid + 1536];
            float4 v4 = L4[tid + 2048];
            zsum += esum4(v0) + esum4(v1) + esum4(v2) + esum4(v3) + esum4(v4);
        }
        {
            float4 v0 = L4[tid + 2560];
            float4 v1 = L4[tid + 3072];
            float4 v2 = L4[tid + 3584];
            float4 v3 = L4[tid + 4096];
            float4 v4 = L4[tid + 4608];
            zsum += esum4(v0) + esum4(v1) + esum4(v2) + esum4(v3) + esum4(v4);
        }
        {
            float4 v0 = L4[tid + 5120];
            float4 v1 = L4[tid + 5632];
            float4 v2 = L4[tid + 6144];
            float4 v3 = L4[tid + 6656];
            float4 v4 = L4[tid + 7168];
            zsum += esum4(v0) + esum4(v1) + esum4(v2) + esum4(v3) + esum4(v4);
        }
        if (tid < NV4 - 7680) {  // 320 tail float4s
            zsum += esum4(L4[tid + 7680]);
        }
    };

    // block-parity phase swap (block-uniform branch, no divergence)
    if (blockIdx.x & 1) { do_small(); do_stream(); }
    else                { do_stream(); do_small(); }

    // ---- reduce {Z, gate}: wave shfl -> LDS atomicAdd -> one barrier ----
    for (int off = 32; off > 0; off >>= 1) {
        zsum += __shfl_down(zsum, off, 64);
        gsum += __shfl_down(gsum, off, 64);
    }
    if ((tid & 63) == 0) {
        atomicAdd(&sZ, zsum);
        atomicAdd(&sG, gsum);
    }
    __syncthreads();  // B2: sZ/sG final; hash inserts also complete

    // finalize duplicated across all threads (cheaper than barrier + bcast)
    const float G  = sG + b_logits[0] + b_embeds[0] + b_enc[0] + bias[0];
    const float p  = 1.f / (1.f + __expf(-G));
    const float a  = (1.f - p) / sZ;
    const float la = __logf(a);  // -inf if p saturates; slow path handles it

    // ---- pass B: re-read row (L2/L3-hot), transform, store.
    // Fast path: tx = x + la; for tx > -20 the dropped EPS term is < 5e-4.
    float4* O4 = (float4*)(out + (size_t)row * NV);
#define XFRM(v) { float tx;                                                \
        tx = v.x + la; v.x = (tx > -20.f) ? tx : __logf(__expf(tx) + EPS); \
        tx = v.y + la; v.y = (tx > -20.f) ? tx : __logf(__expf(tx) + EPS); \
        tx = v.z + la; v.z = (tx > -20.f) ? tx : __logf(__expf(tx) + EPS); \
        tx = v.w + la; v.w = (tx > -20.f) ? tx : __logf(__expf(tx) + EPS); }
    {
        float4 v0 = L4[tid];
        float4 v1 = L4[tid + 512];
        float4 v2 = L4[tid + 1024];
        float4 v3 = L4[tid + 1536];
        float4 v4 = L4[tid + 2048];
        XFRM(v0); O4[tid]        = v0;
        XFRM(v1); O4[tid + 512]  = v1;
        XFRM(v2); O4[tid + 1024] = v2;
        XFRM(v3); O4[tid + 1536] = v3;
        XFRM(v4); O4[tid + 2048] = v4;
    }
    {
        float4 v0 = L4[tid + 2560];
        float4 v1 = L4[tid + 3072];
        float4 v2 = L4[tid + 3584];
        float4 v3 = L4[tid + 4096];
        float4 v4 = L4[tid + 4608];
        XFRM(v0); O4[tid + 2560] = v0;
        XFRM(v1); O4[tid + 3072] = v1;
        XFRM(v2); O4[tid + 3584] = v2;
        XFRM(v3); O4[tid + 4096] = v3;
        XFRM(v4); O4[tid + 4608] = v4;
    }
    {
        float4 v0 = L4[tid + 5120];
        float4 v1 = L4[tid + 5632];
        float4 v2 = L4[tid + 6144];
        float4 v3 = L4[tid + 6656];
        float4 v4 = L4[tid + 7168];
        XFRM(v0); O4[tid + 5120] = v0;
        XFRM(v1); O4[tid + 5632] = v1;
        XFRM(v2); O4[tid + 6144] = v2;
        XFRM(v3); O4[tid + 6656] = v3;
        XFRM(v4); O4[tid + 7168] = v4;
    }
    if (tid < NV4 - 7680) {
        float4 v = L4[tid + 7680];
        XFRM(v); O4[tid + 7680] = v;
    }
#undef XFRM
    __syncthreads();  // B3: drain block's stores (vmcnt) before fixup

    // ---- fixup: overwrite copy positions with full expression ----
    for (int i = tid; i < HSIZE; i += BLK) {
        int id = hkey[i];
        if (id >= 0) {
            float x = logits[(size_t)row * NV + id];
            out[(size_t)row * NV + id] = __logf(a * __expf(x) + p * hval[i] + EPS);
        }
    }
}

// ---------------------------------------------------------------------------
extern "C" void kernel_launch(void* const* d_in, const int* in_sizes, int n_in,
                              void* d_out, int out_size, void* d_ws, size_t ws_size,
                              hipStream_t stream) {
    const float* dec_attn = (const float*)d_in[0];   // (B,H,T,S)
    const float* dlhs     = (const float*)d_in[1];   // (B,T,D)
    const int*   ids      = (const int*)d_in[2];     // (B,S) int32
    const float* logits   = (const float*)d_in[3];   // (B,T,V)
    const float* die      = (const float*)d_in[4];   // (B,T,D)
    const float* enc      = (const float*)d_in[5];   // (B,S,D)
    const float* w_logits = (const float*)d_in[6];   // (D,)
    const float* b_logits = (const float*)d_in[7];   // scalar
    const float* w_embeds = (const float*)d_in[8];   // (D,)
    const float* b_embeds = (const float*)d_in[9];   // scalar
    const float* w_enc    = (const float*)d_in[10];  // (D,)
    const float* b_enc    = (const float*)d_in[11];  // scalar
    const float* bias     = (const float*)d_in[12];  // scalar
    float* out = (float*)d_out;

    float* e_proj = (float*)d_ws;                    // NB*NS fp32 (8 KB)

    {   // K2: e_proj = E @ w_enc
        int waves = NB * NS;
        eproj_kernel<<<(waves * 64) / 256, 256, 0, stream>>>(enc, w_enc, e_proj);
    }
    {   // Mega kernel: everything else, one 512-thread block per (b,t) row
        out_kernel<<<NB * NT, BLK, 0, stream>>>(
            dec_attn, logits, ids, dlhs, die, e_proj,
            w_logits, w_embeds, b_logits, b_embeds, b_enc, bias, out);
    }
}